// Round 4
// baseline (67.703 us; speedup 1.0000x reference)
//
#include <hip/hip_runtime.h>
#include <math.h>

namespace {
constexpr int kB = 128;
constexpr int kV = 128256;
constexpr int kSplits = 16;
constexpr int kSplit = kV / kSplits;   // 8016
constexpr int kSplit4 = kSplit / 4;    // 2004 float4
constexpr int kT1 = 256;
constexpr int kE = 8;                  // float4 regs/thread: 8*256=2048 >= 2004
constexpr int kCap = 256;              // candidate cap (== kT1, 1 per thread)
constexpr int kTop = 64;               // max top_k

// monotonic uint key: ascending key <=> ascending float
__device__ __forceinline__ unsigned fkey(float y) {
  unsigned u = __float_as_uint(y);
  return ((int)u < 0) ? ~u : (u | 0x80000000u);
}
__device__ __forceinline__ float keyinv(unsigned k) {
  unsigned u = (k & 0x80000000u) ? (k & 0x7fffffffu) : ~k;
  return __uint_as_float(u);
}

__global__ __launch_bounds__(kT1, 6) void k_select(
    const float* __restrict__ logits, const float* __restrict__ temps,
    float* __restrict__ out,
    float* __restrict__ wm, float* __restrict__ wS,
    unsigned long long* __restrict__ wpk) {
  const int sp = blockIdx.x, row = blockIdx.y, tid = threadIdx.x;
  const int lane = tid & 63, wid = tid >> 6;
  __shared__ float red[kT1];
  __shared__ float wmax[4];
  __shared__ int cnt2[2][4];
  __shared__ unsigned long long cand[kCap];
  __shared__ int scnt;

  if (tid == 0) scnt = 0;
  const float t = temps[row];
  const size_t rowbase = (size_t)row * kV + (size_t)sp * kSplit;
  const float4* in4 = (const float4*)(logits + rowbase);
  float4* out4 = (float4*)(out + 2 * kB + rowbase);
  const float nI = -INFINITY;

  // Load split into registers (no stores here — zero-fill moved to kernel
  // end so no __syncthreads ever waits on outstanding global writes).
  float4 r[kE];
  float m = nI;
#pragma unroll
  for (int e = 0; e < kE; ++e) {
    int f = tid + e * kT1;
    float4 l;
    if (f < kSplit4) l = in4[f];
    else l = make_float4(nI, nI, nI, nI);
    float4 y = make_float4(l.x / t, l.y / t, l.z / t, l.w / t);
    r[e] = y;
    m = fmaxf(m, fmaxf(fmaxf(y.x, y.y), fmaxf(y.z, y.w)));
  }
  // Wave shfl max (fmax is order-exact) + 4-way LDS combine: 1 barrier.
  for (int o = 32; o; o >>= 1) m = fmaxf(m, __shfl_xor(m, o));
  if (lane == 0) wmax[wid] = m;
  __syncthreads();
  const float M = fmaxf(fmaxf(wmax[0], wmax[1]), fmaxf(wmax[2], wmax[3]));

  // Exact branch-free sum of exp(y - M); identical per-thread order and
  // identical 256-tree reduction as the absmax==0 version. Pads add 0.
  float s = 0.f;
#pragma unroll
  for (int e = 0; e < kE; ++e) {
    s += expf(r[e].x - M); s += expf(r[e].y - M);
    s += expf(r[e].z - M); s += expf(r[e].w - M);
  }
  red[tid] = s; __syncthreads();
  for (int off = kT1 / 2; off; off >>= 1) {
    if (tid < off) red[tid] += red[tid + off];
    __syncthreads();
  }
  const float Ssp = red[0];

  // Convert registers in place to monotonic keys (pad key = 0x007FFFFF).
#pragma unroll
  for (int e = 0; e < kE; ++e) {
    r[e].x = __uint_as_float(fkey(r[e].x));
    r[e].y = __uint_as_float(fkey(r[e].y));
    r[e].z = __uint_as_float(fkey(r[e].z));
    r[e].w = __uint_as_float(fkey(r[e].w));
  }

  // Threshold search: ballot+popcount counting (compare = 1 VALU; popc and
  // accumulate ride the scalar pipe; ballot itself is the wave reduction).
  // One barrier per iteration via double-buffered wave-count slots.
  // Forced first probe at fkey(M-16) collapses the bracket.
  unsigned lo = 0x00800000u;          // >= all finite y; excludes -inf pads
  unsigned hi = fkey(M) + 1;          // count 0
  for (int it = 0; it < 32 && hi - lo > 1; ++it) {
    unsigned mid = (it == 0) ? fkey(M - 16.0f) : lo + ((hi - lo) >> 1);
    if (mid <= lo || mid >= hi) mid = lo + ((hi - lo) >> 1);
    int cw = 0;
#pragma unroll
    for (int e = 0; e < kE; ++e) {
      cw += (int)__popcll(__ballot(__float_as_uint(r[e].x) >= mid));
      cw += (int)__popcll(__ballot(__float_as_uint(r[e].y) >= mid));
      cw += (int)__popcll(__ballot(__float_as_uint(r[e].z) >= mid));
      cw += (int)__popcll(__ballot(__float_as_uint(r[e].w) >= mid));
    }
    if (lane == 0) cnt2[it & 1][wid] = cw;
    __syncthreads();
    const int c = cnt2[it & 1][0] + cnt2[it & 1][1] +
                  cnt2[it & 1][2] + cnt2[it & 1][3];
    if (c >= kTop) { lo = mid; if (c <= kCap) break; }
    else hi = mid;
  }
  const unsigned T = lo;

  // Ballot-compacted candidate collection: 1 atomic per wave per nonzero
  // mask (slot order nondeterministic; the sort below restores determinism).
#pragma unroll
  for (int e = 0; e < kE; ++e) {
    int f = tid + e * kT1;
    unsigned kx[4] = {__float_as_uint(r[e].x), __float_as_uint(r[e].y),
                      __float_as_uint(r[e].z), __float_as_uint(r[e].w)};
#pragma unroll
    for (int j = 0; j < 4; ++j) {
      bool p = kx[j] >= T;
      unsigned long long mk = __ballot(p);
      if (mk) {
        int base = 0;
        if (lane == 0) base = atomicAdd(&scnt, (int)__popcll(mk));
        base = __shfl(base, 0);
        if (p) {
          int pos = base + (int)__popcll(mk & ((1ULL << lane) - 1ULL));
          if (pos < kCap)
            cand[pos] = ((unsigned long long)kx[j] << 32) |
                        (unsigned)~(unsigned)(sp * kSplit + f * 4 + j);
        }
      }
    }
  }
  __syncthreads();
  if (tid >= (scnt < kCap ? scnt : kCap)) cand[tid] = 0ULL;

  // Bitonic sort 256 desc, one element per thread.
  for (int k2 = 2; k2 <= kCap; k2 <<= 1)
    for (int j = k2 >> 1; j; j >>= 1) {
      __syncthreads();
      int ixj = tid ^ j;
      if (ixj > tid) {
        unsigned long long a = cand[tid], b = cand[ixj];
        bool desc = ((tid & k2) == 0);
        if (desc ? (a < b) : (a > b)) { cand[tid] = b; cand[ixj] = a; }
      }
    }
  __syncthreads();

  if (tid < kTop)
    wpk[((size_t)row * kSplits + sp) * kTop + tid] = cand[tid];
  if (tid == 0) {
    wm[row * kSplits + sp] = M;
    wS[row * kSplits + sp] = Ssp;
  }

  // Zero-fill the output split LAST: stores drain with no barrier behind
  // them, overlapping other blocks' compute and the kernel boundary.
  const float4 z4 = make_float4(0.f, 0.f, 0.f, 0.f);
#pragma unroll
  for (int e = 0; e < kE; ++e) {
    int f = tid + e * kT1;
    if (f < kSplit4) out4[f] = z4;
  }
}

__global__ __launch_bounds__(kT1) void k_sample(
    const int* __restrict__ top_ks, const float* __restrict__ top_ps,
    const float* __restrict__ uin,
    const float* __restrict__ wm, const float* __restrict__ wS,
    const unsigned long long* __restrict__ wpk, float* __restrict__ out) {
  const int row = blockIdx.x, tid = threadIdx.x;
  constexpr int kN = kSplits * kTop;   // 1024
  __shared__ unsigned long long pk[kN];
  __shared__ float mArr[kSplits], sArr[kSplits];
  __shared__ float tv[kTop];
  __shared__ int ti[kTop];
  __shared__ float sv[kTop];
  __shared__ float MS[2];

  if (tid < kSplits) {
    mArr[tid] = wm[row * kSplits + tid];
    sArr[tid] = wS[row * kSplits + tid];
  }
  for (int i = tid; i < kN; i += kT1)
    pk[i] = wpk[(size_t)row * kN + i];
  __syncthreads();
  if (tid == 0) {  // fixed-order merge of split (m, S) partials
    float M = -INFINITY;
    for (int s2 = 0; s2 < kSplits; ++s2) M = fmaxf(M, mArr[s2]);
    float S = 0.f;
    for (int s2 = 0; s2 < kSplits; ++s2) S += expf(mArr[s2] - M) * sArr[s2];
    MS[0] = M; MS[1] = S;
  }

  // Bitonic top-64 merge: 4 rounds of (cross-compare + 6 cleanup stages).
  for (int r = 0; r < 4; ++r) {
    const int pairs = 8 >> r;
    __syncthreads();
    for (int w = tid; w < pairs * 64; w += kT1) {
      int q = w >> 6, i = w & 63;
      int a = q * (128 << r), b = a + (64 << r);
      unsigned long long x = pk[a + i], y = pk[b + 63 - i];
      pk[a + i] = x > y ? x : y;      // top-64 multiset, bitonic order
    }
    for (int j = 32; j; j >>= 1) {    // desc bitonic merge of each kept run
      __syncthreads();
      for (int w = tid; w < pairs * 32; w += kT1) {
        int q = w >> 5, z = w & 31;
        int a = q * (128 << r);
        int i = ((z & ~(j - 1)) << 1) | (z & (j - 1));
        unsigned long long x = pk[a + i], y = pk[a + i + j];
        if (x < y) { pk[a + i] = y; pk[a + i + j] = x; }
      }
    }
  }
  __syncthreads();

  if (tid < kTop) {
    unsigned long long p2 = pk[tid];
    tv[tid] = keyinv((unsigned)(p2 >> 32));
    ti[tid] = (int)(~(unsigned)(p2 & 0xffffffffu));
  }
  __syncthreads();

  if (tid == 0) {  // exact reference-order serial epilogue (absmax 0 x3)
    const float M = MS[0], S = MS[1];
    const float tp = top_ps[row];
    const int kk = top_ks[row];
    const float uu = uin[row];
    float cum = 0.f;
    float qa[kTop];
#pragma unroll
    for (int r = 0; r < kTop; ++r) {
      float pr = expf(tv[r] - M) / S;          // prob of rank r
      cum += pr;
      float cb = cum - pr;                     // cumulative BEFORE this token
      qa[r] = ((cb > tp) || (r >= kk)) ? 0.f : pr;
    }
    const float q0 = qa[0];                    // rank 0 never masked
    float tot = 0.f;
    float cdfa[kTop];
#pragma unroll
    for (int r = 0; r < kTop; ++r) {
      float sr = qa[r] / q0;
      sv[r] = sr;
      tot += sr;
      cdfa[r] = tot;
    }
    const float rth = uu * tot;
    int cnt = 0;
#pragma unroll
    for (int r = 0; r < kTop; ++r) cnt += (cdfa[r] < rth) ? 1 : 0;
    if (cnt > kTop - 1) cnt = kTop - 1;
    out[row] = (float)ti[cnt];                 // sampled token id
    out[kB + row] = 1.0f;                      // success
  }
  __syncthreads();
  if (tid < kTop) out[2 * kB + (size_t)row * kV + tid] = sv[tid];
}
}  // namespace

extern "C" void kernel_launch(void* const* d_in, const int* in_sizes, int n_in,
                              void* d_out, int out_size, void* d_ws, size_t ws_size,
                              hipStream_t stream) {
  const float* logits = (const float*)d_in[0];
  const float* temps  = (const float*)d_in[1];
  const int*   top_ks = (const int*)d_in[2];
  const float* top_ps = (const float*)d_in[3];
  const float* uin    = (const float*)d_in[4];
  float* out = (float*)d_out;

  // workspace layout (~1.1 MB)
  float* wm = (float*)d_ws;                          // [B*Splits] split max
  float* wS = wm + kB * kSplits;                     // [B*Splits] split sumexp
  unsigned long long* wpk =                          // [B*Splits*Top] sorted top-64
      (unsigned long long*)(wS + kB * kSplits + kB * kSplits);

  k_select<<<dim3(kSplits, kB), kT1, 0, stream>>>(logits, temps, out, wm, wS, wpk);
  k_sample<<<kB, kT1, 0, stream>>>(top_ks, top_ps, uin, wm, wS, wpk, out);
}